// Round 1
// baseline (1938.338 us; speedup 1.0000x reference)
//
#include <hip/hip_runtime.h>
#include <hip/hip_bf16.h>
#include <math.h>

#define DIM 64
#define HID 128

// ---------------- node init: deg=1 (self loop) + clip scale per entity row ----
__global__ __launch_bounds__(256) void node_init(const float* __restrict__ emb,
                                                 float* __restrict__ deg,
                                                 float* __restrict__ xs,
                                                 int n_nodes) {
    int lane = threadIdx.x & 63;
    int wid = (blockIdx.x * 256 + threadIdx.x) >> 6;
    if (wid >= n_nodes) return;
    float v = emb[(size_t)wid * DIM + lane];
    float s = v * v;
    #pragma unroll
    for (int off = 32; off; off >>= 1) s += __shfl_xor(s, off);
    if (lane == 0) {
        float nrm = sqrtf(s);
        xs[wid] = fminf(1.0f, 1.0f / (nrm + 1e-7f));
        deg[wid] = 1.0f;
    }
}

// ---------------- degree accumulation over edges ------------------------------
__global__ void deg_kernel(const int* __restrict__ dst, float* __restrict__ deg, int nedges) {
    int i = blockIdx.x * blockDim.x + threadIdx.x;
    int n = gridDim.x * blockDim.x;
    for (int e = i; e < nedges; e += n) atomicAdd(&deg[dst[e]], 1.0f);
}

// ---------------- dinv = rsqrt(deg), in place (deg >= 1 always) ---------------
__global__ void dinv_kernel(float* __restrict__ deg, int n_nodes) {
    int i = blockIdx.x * blockDim.x + threadIdx.x;
    if (i < n_nodes) deg[i] = rsqrtf(deg[i]);
}

// ---------------- GEMM1: xw = (x * xs) @ W1 ; acc1 = xw * dinv^2 --------------
// W1: [64,128] row-major. Block of 256 threads handles 16 rows.
__global__ __launch_bounds__(256) void gemm1(const float* __restrict__ x,
                                             const float* __restrict__ xs,
                                             const float* __restrict__ W1,
                                             const float* __restrict__ dinv,
                                             float* __restrict__ xw,
                                             float* __restrict__ acc1,
                                             int n_nodes) {
    __shared__ float wlds[DIM * HID];   // 32 KB
    __shared__ float xlds[16 * DIM];    // 4 KB
    for (int idx = threadIdx.x; idx < DIM * HID; idx += 256) wlds[idx] = W1[idx];
    int row0 = blockIdx.x * 16;
    for (int idx = threadIdx.x; idx < 16 * DIM; idx += 256) {
        int r = idx / DIM, d = idx % DIM;
        int n = row0 + r;
        float v = 0.0f;
        if (n < n_nodes) v = x[(size_t)n * DIM + d] * xs[n];
        xlds[idx] = v;
    }
    __syncthreads();
    int hq = threadIdx.x & 31;        // output quad: h0 = hq*4  (128 = 32 quads)
    int rsub = threadIdx.x >> 5;      // 0..7
    #pragma unroll
    for (int rr0 = 0; rr0 < 2; ++rr0) {
        int rr = rsub + rr0 * 8;
        int n = row0 + rr;
        if (n >= n_nodes) continue;
        float4 acc = {0.f, 0.f, 0.f, 0.f};
        #pragma unroll 8
        for (int d = 0; d < DIM; ++d) {
            float xv = xlds[rr * DIM + d];
            float4 w = *(const float4*)&wlds[d * HID + hq * 4];
            acc.x += xv * w.x; acc.y += xv * w.y;
            acc.z += xv * w.z; acc.w += xv * w.w;
        }
        float di = dinv[n];
        float di2 = di * di;
        *(float4*)&xw[(size_t)n * HID + hq * 4] = acc;
        float4 a2 = {acc.x * di2, acc.y * di2, acc.z * di2, acc.w * di2};
        *(float4*)&acc1[(size_t)n * HID + hq * 4] = a2;
    }
}

// ---------------- GEMM2: hw = relu(acc1 + b1) @ W2 ; acc2 = hw * dinv^2 -------
// W2: [128,64] row-major. Block of 256 threads handles 16 rows.
__global__ __launch_bounds__(256) void gemm2(const float* __restrict__ acc1,
                                             const float* __restrict__ b1,
                                             const float* __restrict__ W2,
                                             const float* __restrict__ dinv,
                                             float* __restrict__ hw,
                                             float* __restrict__ acc2,
                                             int n_nodes) {
    __shared__ float wlds[HID * DIM];   // 32 KB
    __shared__ float hlds[16 * HID];    // 8 KB
    for (int idx = threadIdx.x; idx < HID * DIM; idx += 256) wlds[idx] = W2[idx];
    int row0 = blockIdx.x * 16;
    for (int idx = threadIdx.x; idx < 16 * HID; idx += 256) {
        int r = idx / HID, k = idx % HID;
        int n = row0 + r;
        float v = 0.0f;
        if (n < n_nodes) v = fmaxf(acc1[(size_t)n * HID + k] + b1[k], 0.0f);
        hlds[idx] = v;
    }
    __syncthreads();
    int oq = threadIdx.x & 15;        // output quad: o0 = oq*4  (64 = 16 quads)
    int rsub = threadIdx.x >> 4;      // 0..15
    int n = row0 + rsub;
    if (n >= n_nodes) return;
    float4 acc = {0.f, 0.f, 0.f, 0.f};
    #pragma unroll 8
    for (int d = 0; d < HID; ++d) {
        float hv = hlds[rsub * HID + d];
        float4 w = *(const float4*)&wlds[d * DIM + oq * 4];
        acc.x += hv * w.x; acc.y += hv * w.y;
        acc.z += hv * w.z; acc.w += hv * w.w;
    }
    float di = dinv[n];
    float di2 = di * di;
    *(float4*)&hw[(size_t)n * DIM + oq * 4] = acc;
    float4 a2 = {acc.x * di2, acc.y * di2, acc.z * di2, acc.w * di2};
    *(float4*)&acc2[(size_t)n * DIM + oq * 4] = a2;
}

// ---------------- edge scatter: acc[dst] += val[src] * dinv[src]*dinv[dst] ----
template <int K>
__global__ __launch_bounds__(256) void scatter_k(const int* __restrict__ src,
                                                 const int* __restrict__ dst,
                                                 const float* __restrict__ dinv,
                                                 const float* __restrict__ val,
                                                 float* __restrict__ acc,
                                                 int nedges) {
    int lane = threadIdx.x & 63;
    int wid = (blockIdx.x * 256 + threadIdx.x) >> 6;
    int nw = (gridDim.x * 256) >> 6;
    for (int e = wid; e < nedges; e += nw) {
        int s = src[e], d = dst[e];
        float w = dinv[s] * dinv[d];
        if (K == 128) {
            float2 v = *(const float2*)&val[(size_t)s * 128 + lane * 2];
            atomicAdd(&acc[(size_t)d * 128 + lane * 2], v.x * w);
            atomicAdd(&acc[(size_t)d * 128 + lane * 2 + 1], v.y * w);
        } else {
            float v = val[(size_t)s * 64 + lane];
            atomicAdd(&acc[(size_t)d * 64 + lane], v * w);
        }
    }
}

// ---------------- final: logit = sigmoid(<clip(user)[u], acc2[i]+b2>) ---------
__global__ __launch_bounds__(256) void final_kernel(const float* __restrict__ user_emb,
                                                    const int* __restrict__ u,
                                                    const int* __restrict__ iid,
                                                    const float* __restrict__ acc2,
                                                    const float* __restrict__ b2,
                                                    float* __restrict__ out,
                                                    int batch) {
    int lane = threadIdx.x & 63;
    int wid = (blockIdx.x * 256 + threadIdx.x) >> 6;
    if (wid >= batch) return;
    int uu = u[wid], ii = iid[wid];
    float uv = user_emb[(size_t)uu * DIM + lane];
    float s = uv * uv;
    #pragma unroll
    for (int off = 32; off; off >>= 1) s += __shfl_xor(s, off);
    float sc = fminf(1.0f, 1.0f / (sqrtf(s) + 1e-7f));
    float iv = acc2[(size_t)ii * DIM + lane] + b2[lane];
    float dot = uv * sc * iv;
    #pragma unroll
    for (int off = 32; off; off >>= 1) dot += __shfl_xor(dot, off);
    if (lane == 0) out[wid] = 1.0f / (1.0f + expf(-dot));
}

extern "C" void kernel_launch(void* const* d_in, const int* in_sizes, int n_in,
                              void* d_out, int out_size, void* d_ws, size_t ws_size,
                              hipStream_t stream) {
    const float* entity = (const float*)d_in[0];
    const float* user   = (const float*)d_in[1];
    const float* W1     = (const float*)d_in[2];
    const float* b1     = (const float*)d_in[3];
    const float* W2     = (const float*)d_in[4];
    const float* b2     = (const float*)d_in[5];
    const int*   u      = (const int*)d_in[6];
    const int*   iid    = (const int*)d_in[7];
    const int*   eidx   = (const int*)d_in[8];

    int N = in_sizes[0] / DIM;      // 100000
    int B = in_sizes[6];            // 8192
    int E = in_sizes[8] / 2;        // 1600000
    const int* src = eidx;
    const int* dst = eidx + E;

    float* ws   = (float*)d_ws;
    float* deg  = ws;                                   // N floats (becomes dinv)
    float* xs   = ws + N;                               // N floats
    float* xw   = ws + 262144;                          // N*128 floats (A region)
    float* acc1 = xw + (size_t)N * HID;                 // N*128 floats (B region)
    float* hw   = xw;                                   // reuse A region: N*64
    float* acc2 = xw + (size_t)N * DIM;                 // A region second half: N*64
    float* outF = (float*)d_out;

    node_init<<<(N * 64 + 255) / 256, 256, 0, stream>>>(entity, deg, xs, N);
    deg_kernel<<<2048, 256, 0, stream>>>(dst, deg, E);
    dinv_kernel<<<(N + 255) / 256, 256, 0, stream>>>(deg, N);
    gemm1<<<(N + 15) / 16, 256, 0, stream>>>(entity, xs, W1, deg, xw, acc1, N);
    scatter_k<128><<<8192, 256, 0, stream>>>(src, dst, deg, xw, acc1, E);
    gemm2<<<(N + 15) / 16, 256, 0, stream>>>(acc1, b1, W2, deg, hw, acc2, N);
    scatter_k<64><<<8192, 256, 0, stream>>>(src, dst, deg, hw, acc2, E);
    final_kernel<<<(B * 64 + 255) / 256, 256, 0, stream>>>(user, u, iid, acc2, b2, outF, B);
}

// Round 3
// 741.071 us; speedup vs baseline: 2.6156x; 2.6156x over previous
//
#include <hip/hip_runtime.h>
#include <hip/hip_bf16.h>
#include <math.h>

#define DIM 64
#define HID 128

// ---- node init: clip scale per entity row + zero edge-count -----------------
__global__ __launch_bounds__(256) void node_init(const float* __restrict__ emb,
                                                 int* __restrict__ cnt,
                                                 float* __restrict__ xs,
                                                 int n_nodes) {
    int lane = threadIdx.x & 63;
    int wid = (blockIdx.x * 256 + threadIdx.x) >> 6;
    if (wid >= n_nodes) return;
    float v = emb[(size_t)wid * DIM + lane];
    float s = v * v;
    #pragma unroll
    for (int off = 32; off; off >>= 1) s += __shfl_xor(s, off);
    if (lane == 0) {
        xs[wid] = fminf(1.0f, 1.0f / (sqrtf(s) + 1e-7f));
        cnt[wid] = 0;
    }
}

// ---- histogram of dst ------------------------------------------------------
__global__ void hist_kernel(const int* __restrict__ dst, int* __restrict__ cnt, int nedges) {
    int i = blockIdx.x * blockDim.x + threadIdx.x;
    int n = gridDim.x * blockDim.x;
    for (int e = i; e < nedges; e += n) atomicAdd(&cnt[dst[e]], 1);
}

// ---- single-block scan: rowptr = exclusive-prefix(cnt); dinv; cnt=0 --------
__global__ __launch_bounds__(1024) void scan_kernel(int* __restrict__ cnt,
                                                    int* __restrict__ rowptr,
                                                    float* __restrict__ dinv,
                                                    int N) {
    __shared__ int wsums[16];
    __shared__ int carry_s;
    int lane = threadIdx.x & 63;
    int wid = threadIdx.x >> 6;
    if (threadIdx.x == 0) carry_s = 0;
    __syncthreads();
    for (int base = 0; base < N; base += 1024) {
        int i = base + threadIdx.x;
        int v = (i < N) ? cnt[i] : 0;
        int x = v;
        #pragma unroll
        for (int off = 1; off < 64; off <<= 1) {
            int y = __shfl_up(x, off, 64);
            if (lane >= off) x += y;
        }
        if (lane == 63) wsums[wid] = x;
        __syncthreads();
        if (wid == 0) {
            int t = (lane < 16) ? wsums[lane] : 0;
            #pragma unroll
            for (int off = 1; off < 16; off <<= 1) {
                int y = __shfl_up(t, off, 64);
                if (lane >= off) t += y;
            }
            if (lane < 16) wsums[lane] = t;   // inclusive wave sums
        }
        __syncthreads();
        int waveoff = (wid == 0) ? 0 : wsums[wid - 1];
        int carry = carry_s;
        int excl = carry + waveoff + x - v;
        if (i < N) {
            rowptr[i] = excl;
            dinv[i] = rsqrtf((float)(1 + v));   // +1 self loop, deg>=1 always
            cnt[i] = 0;                          // reset for placement pass
        }
        __syncthreads();
        if (threadIdx.x == 1023) carry_s = excl + v;
    }
    __syncthreads();
    if (threadIdx.x == 0) rowptr[N] = carry_s;
}

// ---- placement: bucket edges by dst, store src id + edge weight ------------
__global__ void place_kernel(const int* __restrict__ src, const int* __restrict__ dst,
                             const int* __restrict__ rowptr, int* __restrict__ cnt,
                             const float* __restrict__ dinv,
                             int* __restrict__ srcs, float* __restrict__ wgt, int nedges) {
    int i = blockIdx.x * blockDim.x + threadIdx.x;
    int n = gridDim.x * blockDim.x;
    for (int e = i; e < nedges; e += n) {
        int s = src[e], d = dst[e];
        int slot = rowptr[d] + atomicAdd(&cnt[d], 1);
        srcs[slot] = s;
        wgt[slot] = dinv[s] * dinv[d];
    }
}

// ---- GEMM1: xw = (x * xs) @ W1 ---------------------------------------------
__global__ __launch_bounds__(256) void gemm1(const float* __restrict__ x,
                                             const float* __restrict__ xs,
                                             const float* __restrict__ W1,
                                             float* __restrict__ xw,
                                             int n_nodes) {
    __shared__ float wlds[DIM * HID];   // 32 KB
    __shared__ float xlds[16 * DIM];    // 4 KB
    for (int idx = threadIdx.x; idx < DIM * HID; idx += 256) wlds[idx] = W1[idx];
    int row0 = blockIdx.x * 16;
    for (int idx = threadIdx.x; idx < 16 * DIM; idx += 256) {
        int r = idx / DIM, d = idx % DIM;
        int n = row0 + r;
        float v = 0.0f;
        if (n < n_nodes) v = x[(size_t)n * DIM + d] * xs[n];
        xlds[idx] = v;
    }
    __syncthreads();
    int hq = threadIdx.x & 31;
    int rsub = threadIdx.x >> 5;
    #pragma unroll
    for (int rr0 = 0; rr0 < 2; ++rr0) {
        int rr = rsub + rr0 * 8;
        int n = row0 + rr;
        if (n >= n_nodes) continue;
        float4 acc = {0.f, 0.f, 0.f, 0.f};
        #pragma unroll 8
        for (int d = 0; d < DIM; ++d) {
            float xv = xlds[rr * DIM + d];
            float4 w = *(const float4*)&wlds[d * HID + hq * 4];
            acc.x += xv * w.x; acc.y += xv * w.y;
            acc.z += xv * w.z; acc.w += xv * w.w;
        }
        *(float4*)&xw[(size_t)n * HID + hq * 4] = acc;
    }
}

// ---- GEMM2: hw = relu(acc1 + b1) @ W2 --------------------------------------
__global__ __launch_bounds__(256) void gemm2(const float* __restrict__ acc1,
                                             const float* __restrict__ b1,
                                             const float* __restrict__ W2,
                                             float* __restrict__ hw,
                                             int n_nodes) {
    __shared__ float wlds[HID * DIM];   // 32 KB
    __shared__ float hlds[16 * HID];    // 8 KB
    for (int idx = threadIdx.x; idx < HID * DIM; idx += 256) wlds[idx] = W2[idx];
    int row0 = blockIdx.x * 16;
    for (int idx = threadIdx.x; idx < 16 * HID; idx += 256) {
        int r = idx / HID, k = idx % HID;
        int n = row0 + r;
        float v = 0.0f;
        if (n < n_nodes) v = fmaxf(acc1[(size_t)n * HID + k] + b1[k], 0.0f);
        hlds[idx] = v;
    }
    __syncthreads();
    int oq = threadIdx.x & 15;
    int rsub = threadIdx.x >> 4;
    int n = row0 + rsub;
    if (n >= n_nodes) return;
    float4 acc = {0.f, 0.f, 0.f, 0.f};
    #pragma unroll 8
    for (int d = 0; d < HID; ++d) {
        float hv = hlds[rsub * HID + d];
        float4 w = *(const float4*)&wlds[d * DIM + oq * 4];
        acc.x += hv * w.x; acc.y += hv * w.y;
        acc.z += hv * w.z; acc.w += hv * w.w;
    }
    *(float4*)&hw[(size_t)n * DIM + oq * 4] = acc;
}

// ---- CSR gather: out[d] = val[d]*dinv[d]^2 + sum_e val[src_e]*wgt_e --------
template <int K>
__global__ __launch_bounds__(256) void gather_k(const int* __restrict__ rowptr,
                                                const int* __restrict__ srcs,
                                                const float* __restrict__ wgt,
                                                const float* __restrict__ dinv,
                                                const float* __restrict__ val,
                                                float* __restrict__ out,
                                                int n_nodes) {
    int lane = threadIdx.x & 63;
    int node = (blockIdx.x * 256 + threadIdx.x) >> 6;
    if (node >= n_nodes) return;
    int beg = rowptr[node], end = rowptr[node + 1];
    float di = dinv[node];
    float di2 = di * di;
    if (K == 128) {
        float2 acc = *(const float2*)&val[(size_t)node * 128 + lane * 2];
        acc.x *= di2; acc.y *= di2;
        int p = beg;
        for (; p + 1 < end; p += 2) {
            int s0 = srcs[p], s1 = srcs[p + 1];
            float w0 = wgt[p], w1 = wgt[p + 1];
            float2 v0 = *(const float2*)&val[(size_t)s0 * 128 + lane * 2];
            float2 v1 = *(const float2*)&val[(size_t)s1 * 128 + lane * 2];
            acc.x += v0.x * w0; acc.y += v0.y * w0;
            acc.x += v1.x * w1; acc.y += v1.y * w1;
        }
        if (p < end) {
            int s = srcs[p]; float w = wgt[p];
            float2 v = *(const float2*)&val[(size_t)s * 128 + lane * 2];
            acc.x += v.x * w; acc.y += v.y * w;
        }
        *(float2*)&out[(size_t)node * 128 + lane * 2] = acc;
    } else {
        float acc = val[(size_t)node * 64 + lane] * di2;
        int p = beg;
        for (; p + 1 < end; p += 2) {
            int s0 = srcs[p], s1 = srcs[p + 1];
            float w0 = wgt[p], w1 = wgt[p + 1];
            float v0 = val[(size_t)s0 * 64 + lane];
            float v1 = val[(size_t)s1 * 64 + lane];
            acc += v0 * w0 + v1 * w1;
        }
        if (p < end) acc += val[(size_t)srcs[p] * 64 + lane] * wgt[p];
        out[(size_t)node * 64 + lane] = acc;
    }
}

// ---- final: logit = sigmoid(<clip(user)[u], acc2[i]+b2>) -------------------
__global__ __launch_bounds__(256) void final_kernel(const float* __restrict__ user_emb,
                                                    const int* __restrict__ u,
                                                    const int* __restrict__ iid,
                                                    const float* __restrict__ acc2,
                                                    const float* __restrict__ b2,
                                                    float* __restrict__ out,
                                                    int batch) {
    int lane = threadIdx.x & 63;
    int wid = (blockIdx.x * 256 + threadIdx.x) >> 6;
    if (wid >= batch) return;
    int uu = u[wid], ii = iid[wid];
    float uv = user_emb[(size_t)uu * DIM + lane];
    float s = uv * uv;
    #pragma unroll
    for (int off = 32; off; off >>= 1) s += __shfl_xor(s, off);
    float sc = fminf(1.0f, 1.0f / (sqrtf(s) + 1e-7f));
    float iv = acc2[(size_t)ii * DIM + lane] + b2[lane];
    float dot = uv * sc * iv;
    #pragma unroll
    for (int off = 32; off; off >>= 1) dot += __shfl_xor(dot, off);
    if (lane == 0) out[wid] = 1.0f / (1.0f + expf(-dot));
}

extern "C" void kernel_launch(void* const* d_in, const int* in_sizes, int n_in,
                              void* d_out, int out_size, void* d_ws, size_t ws_size,
                              hipStream_t stream) {
    const float* entity = (const float*)d_in[0];
    const float* user   = (const float*)d_in[1];
    const float* W1     = (const float*)d_in[2];
    const float* b1     = (const float*)d_in[3];
    const float* W2     = (const float*)d_in[4];
    const float* b2     = (const float*)d_in[5];
    const int*   u      = (const int*)d_in[6];
    const int*   iid    = (const int*)d_in[7];
    const int*   eidx   = (const int*)d_in[8];

    int N = in_sizes[0] / DIM;      // 100000
    int B = in_sizes[6];            // 8192
    int E = in_sizes[8] / 2;        // 1600000
    const int* src = eidx;
    const int* dst = eidx + E;

    // workspace layout (4-byte units)
    char* wsb = (char*)d_ws;
    int*   cnt    = (int*)wsb;                         // N
    int*   rowptr = cnt + N;                           // N+1
    int*   srcs   = rowptr + N + 1;                    // E
    float* dinv   = (float*)(srcs + E);                // N
    float* xs     = dinv + N;                          // N
    float* wgt    = xs + N;                            // E
    float* xw     = wgt + E;                           // N*128
    float* acc1   = xw + (size_t)N * HID;              // N*128
    float* hw     = xw;                                // reuse: N*64
    float* acc2   = xw + (size_t)N * DIM;              // reuse: N*64
    float* outF   = (float*)d_out;

    node_init<<<(N * 64 + 255) / 256, 256, 0, stream>>>(entity, cnt, xs, N);
    hist_kernel<<<1024, 256, 0, stream>>>(dst, cnt, E);
    scan_kernel<<<1, 1024, 0, stream>>>(cnt, rowptr, dinv, N);
    place_kernel<<<2048, 256, 0, stream>>>(src, dst, rowptr, cnt, dinv, srcs, wgt, E);
    gemm1<<<(N + 15) / 16, 256, 0, stream>>>(entity, xs, W1, xw, N);
    gather_k<128><<<(N * 64 + 255) / 256, 256, 0, stream>>>(rowptr, srcs, wgt, dinv, xw, acc1, N);
    gemm2<<<(N + 15) / 16, 256, 0, stream>>>(acc1, b1, W2, hw, N);
    gather_k<64><<<(N * 64 + 255) / 256, 256, 0, stream>>>(rowptr, srcs, wgt, dinv, hw, acc2, N);
    final_kernel<<<(B * 64 + 255) / 256, 256, 0, stream>>>(user, u, iid, acc2, b2, outF, B);
}

// Round 4
// 532.971 us; speedup vs baseline: 3.6369x; 1.3905x over previous
//
#include <hip/hip_runtime.h>
#include <hip/hip_bf16.h>
#include <math.h>

#define DIM 64
#define HID 128

// ---- node init: xc = clip_max_norm(entity) row-wise; cnt = 0 ----------------
__global__ __launch_bounds__(256) void node_init(const float* __restrict__ emb,
                                                 int* __restrict__ cnt,
                                                 float* __restrict__ xc,
                                                 int n_nodes) {
    int lane = threadIdx.x & 63;
    int wid = (blockIdx.x * 256 + threadIdx.x) >> 6;
    if (wid >= n_nodes) return;
    float v = emb[(size_t)wid * DIM + lane];
    float s = v * v;
    #pragma unroll
    for (int off = 32; off; off >>= 1) s += __shfl_xor(s, off);
    float sc = fminf(1.0f, 1.0f / (sqrtf(s) + 1e-7f));
    xc[(size_t)wid * DIM + lane] = v * sc;
    if (lane == 0) cnt[wid] = 0;
}

// ---- histogram of dst ------------------------------------------------------
__global__ void hist_kernel(const int* __restrict__ dst, int* __restrict__ cnt, int nedges) {
    int i = blockIdx.x * blockDim.x + threadIdx.x;
    int n = gridDim.x * blockDim.x;
    for (int e = i; e < nedges; e += n) atomicAdd(&cnt[dst[e]], 1);
}

// ---- scan phase 1: per-block exclusive scan of cnt; dinv; cnt=0 -------------
__global__ __launch_bounds__(1024) void scan1(int* __restrict__ cnt,
                                              int* __restrict__ rowptr,
                                              int* __restrict__ bsum,
                                              float* __restrict__ dinv,
                                              int N) {
    __shared__ int wsums[16];
    int tid = threadIdx.x, lane = tid & 63, wid = tid >> 6;
    int i = blockIdx.x * 1024 + tid;
    int v = (i < N) ? cnt[i] : 0;
    int x = v;
    #pragma unroll
    for (int off = 1; off < 64; off <<= 1) {
        int y = __shfl_up(x, off, 64);
        if (lane >= off) x += y;
    }
    if (lane == 63) wsums[wid] = x;
    __syncthreads();
    if (wid == 0) {
        int t = (lane < 16) ? wsums[lane] : 0;
        #pragma unroll
        for (int off = 1; off < 16; off <<= 1) {
            int y = __shfl_up(t, off, 64);
            if (lane >= off) t += y;
        }
        if (lane < 16) wsums[lane] = t;
    }
    __syncthreads();
    int woff = wid ? wsums[wid - 1] : 0;
    int excl = woff + x - v;
    if (i < N) {
        rowptr[i] = excl;
        dinv[i] = rsqrtf((float)(1 + v));   // +1 self loop; deg >= 1 always
        cnt[i] = 0;                          // reset as placement cursor
    }
    if (tid == 0) bsum[blockIdx.x] = wsums[15];
}

// ---- scan phase 2: single block exclusive scan of block sums (NB <= 1024) ---
__global__ __launch_bounds__(1024) void scan2(const int* __restrict__ bsum,
                                              int* __restrict__ boff,
                                              int NB) {
    __shared__ int wsums[16];
    int tid = threadIdx.x, lane = tid & 63, wid = tid >> 6;
    int v = (tid < NB) ? bsum[tid] : 0;
    int x = v;
    #pragma unroll
    for (int off = 1; off < 64; off <<= 1) {
        int y = __shfl_up(x, off, 64);
        if (lane >= off) x += y;
    }
    if (lane == 63) wsums[wid] = x;
    __syncthreads();
    if (wid == 0) {
        int t = (lane < 16) ? wsums[lane] : 0;
        #pragma unroll
        for (int off = 1; off < 16; off <<= 1) {
            int y = __shfl_up(t, off, 64);
            if (lane >= off) t += y;
        }
        if (lane < 16) wsums[lane] = t;
    }
    __syncthreads();
    int woff = wid ? wsums[wid - 1] : 0;
    if (tid < NB) boff[tid] = woff + x - v;
    if (tid == 0) boff[NB] = wsums[15];   // grand total
}

// ---- scan phase 3: add block offsets; finalize rowptr[N] --------------------
__global__ __launch_bounds__(1024) void scan3(int* __restrict__ rowptr,
                                              const int* __restrict__ boff,
                                              int N, int NB) {
    int i = blockIdx.x * 1024 + threadIdx.x;
    if (i < N) rowptr[i] += boff[blockIdx.x];
    if (i == 0) rowptr[N] = boff[NB];
}

// ---- placement: edge[slot] = {src, dinv[s]*dinv[d]} bucketed by dst ---------
__global__ void place_kernel(const int* __restrict__ src, const int* __restrict__ dst,
                             const int* __restrict__ rowptr, int* __restrict__ cnt,
                             const float* __restrict__ dinv,
                             int2* __restrict__ edge, int nedges) {
    int i = blockIdx.x * blockDim.x + threadIdx.x;
    int n = gridDim.x * blockDim.x;
    for (int e = i; e < nedges; e += n) {
        int s = src[e], d = dst[e];
        int slot = rowptr[d] + atomicAdd(&cnt[d], 1);
        edge[slot] = make_int2(s, __float_as_int(dinv[s] * dinv[d]));
    }
}

// ---- CSR gather (64-wide): out[d] = val[d]*dinv[d]^2 + sum val[s]*w ---------
__global__ __launch_bounds__(256) void gather64(const int* __restrict__ rowptr,
                                                const int2* __restrict__ edge,
                                                const float* __restrict__ dinv,
                                                const float* __restrict__ val,
                                                float* __restrict__ out,
                                                int n_nodes) {
    int lane = threadIdx.x & 63;
    int node = (blockIdx.x * 256 + threadIdx.x) >> 6;
    if (node >= n_nodes) return;
    int beg = rowptr[node], end = rowptr[node + 1];
    float di = dinv[node];
    float acc = val[(size_t)node * DIM + lane] * (di * di);
    int p = beg;
    for (; p + 3 < end; p += 4) {
        int2 e0 = edge[p], e1 = edge[p + 1], e2 = edge[p + 2], e3 = edge[p + 3];
        float v0 = val[(size_t)e0.x * DIM + lane];
        float v1 = val[(size_t)e1.x * DIM + lane];
        float v2 = val[(size_t)e2.x * DIM + lane];
        float v3 = val[(size_t)e3.x * DIM + lane];
        acc += v0 * __int_as_float(e0.y);
        acc += v1 * __int_as_float(e1.y);
        acc += v2 * __int_as_float(e2.y);
        acc += v3 * __int_as_float(e3.y);
    }
    for (; p < end; ++p) {
        int2 e = edge[p];
        acc += val[(size_t)e.x * DIM + lane] * __int_as_float(e.y);
    }
    out[(size_t)node * DIM + lane] = acc;
}

// ---- fused MLP: hw = relu(ax @ W1 + b1) @ W2 (h never materialized) ---------
__global__ __launch_bounds__(256) void fused_mlp(const float* __restrict__ ax,
                                                 const float* __restrict__ W1,
                                                 const float* __restrict__ b1,
                                                 const float* __restrict__ W2,
                                                 float* __restrict__ hw,
                                                 int n_nodes) {
    __shared__ float w1l[DIM * HID];    // 32 KB
    __shared__ float w2l[HID * DIM];    // 32 KB
    __shared__ float xl[16 * DIM];      // 4 KB
    __shared__ float hl[16 * HID];      // 8 KB
    int tid = threadIdx.x;
    for (int idx = tid; idx < DIM * HID; idx += 256) w1l[idx] = W1[idx];
    for (int idx = tid; idx < HID * DIM; idx += 256) w2l[idx] = W2[idx];
    int row0 = blockIdx.x * 16;
    for (int idx = tid; idx < 16 * DIM; idx += 256) {
        int r = idx >> 6, d = idx & 63;
        int n = row0 + r;
        xl[idx] = (n < n_nodes) ? ax[(size_t)n * DIM + d] : 0.0f;
    }
    __syncthreads();
    // stage 1: h[16][128] = relu(ax @ W1 + b1)
    {
        int hq = tid & 31;         // column quad (128 = 32*4)
        int rs = tid >> 5;         // 0..7
        float4 bq = *(const float4*)&b1[hq * 4];
        #pragma unroll
        for (int rr0 = 0; rr0 < 2; ++rr0) {
            int rr = rs + rr0 * 8;
            float4 acc = {0.f, 0.f, 0.f, 0.f};
            #pragma unroll 8
            for (int d = 0; d < DIM; ++d) {
                float xv = xl[rr * DIM + d];
                float4 w = *(const float4*)&w1l[d * HID + hq * 4];
                acc.x += xv * w.x; acc.y += xv * w.y;
                acc.z += xv * w.z; acc.w += xv * w.w;
            }
            acc.x = fmaxf(acc.x + bq.x, 0.f);
            acc.y = fmaxf(acc.y + bq.y, 0.f);
            acc.z = fmaxf(acc.z + bq.z, 0.f);
            acc.w = fmaxf(acc.w + bq.w, 0.f);
            *(float4*)&hl[rr * HID + hq * 4] = acc;
        }
    }
    __syncthreads();
    // stage 2: hw[16][64] = h @ W2
    {
        int oq = tid & 15;         // column quad (64 = 16*4)
        int rs = tid >> 4;         // 0..15
        int n = row0 + rs;
        if (n >= n_nodes) return;
        float4 acc = {0.f, 0.f, 0.f, 0.f};
        #pragma unroll 8
        for (int d = 0; d < HID; ++d) {
            float hv = hl[rs * HID + d];
            float4 w = *(const float4*)&w2l[d * DIM + oq * 4];
            acc.x += hv * w.x; acc.y += hv * w.y;
            acc.z += hv * w.z; acc.w += hv * w.w;
        }
        *(float4*)&hw[(size_t)n * DIM + oq * 4] = acc;
    }
}

// ---- final: logit = sigmoid(<clip(user)[u], acc2[i]+b2>) --------------------
__global__ __launch_bounds__(256) void final_kernel(const float* __restrict__ user_emb,
                                                    const int* __restrict__ u,
                                                    const int* __restrict__ iid,
                                                    const float* __restrict__ acc2,
                                                    const float* __restrict__ b2,
                                                    float* __restrict__ out,
                                                    int batch) {
    int lane = threadIdx.x & 63;
    int wid = (blockIdx.x * 256 + threadIdx.x) >> 6;
    if (wid >= batch) return;
    int uu = u[wid], ii = iid[wid];
    float uv = user_emb[(size_t)uu * DIM + lane];
    float s = uv * uv;
    #pragma unroll
    for (int off = 32; off; off >>= 1) s += __shfl_xor(s, off);
    float sc = fminf(1.0f, 1.0f / (sqrtf(s) + 1e-7f));
    float iv = acc2[(size_t)ii * DIM + lane] + b2[lane];
    float dot = uv * sc * iv;
    #pragma unroll
    for (int off = 32; off; off >>= 1) dot += __shfl_xor(dot, off);
    if (lane == 0) out[wid] = 1.0f / (1.0f + expf(-dot));
}

extern "C" void kernel_launch(void* const* d_in, const int* in_sizes, int n_in,
                              void* d_out, int out_size, void* d_ws, size_t ws_size,
                              hipStream_t stream) {
    const float* entity = (const float*)d_in[0];
    const float* user   = (const float*)d_in[1];
    const float* W1     = (const float*)d_in[2];
    const float* b1     = (const float*)d_in[3];
    const float* W2     = (const float*)d_in[4];
    const float* b2     = (const float*)d_in[5];
    const int*   u      = (const int*)d_in[6];
    const int*   iid    = (const int*)d_in[7];
    const int*   eidx   = (const int*)d_in[8];

    int N = in_sizes[0] / DIM;      // 100000
    int B = in_sizes[6];            // 8192
    int E = in_sizes[8] / 2;        // 1600000
    const int* src = eidx;
    const int* dst = eidx + E;
    int NB = (N + 1023) / 1024;     // 98 (must be <= 1024)

    // workspace layout (4-byte units; int2 region 8B-aligned)
    int*   cnt    = (int*)d_ws;                         // N
    int*   rowptr = cnt + N;                            // N+1
    int*   bsum   = rowptr + N + 1;                     // NB
    int*   boff   = bsum + NB;                          // NB+1
    float* dinv   = (float*)(boff + NB + 1);            // N
    size_t off    = (size_t)(4 * N + 2 * NB + 2);
    off = (off + 1) & ~(size_t)1;                       // 8B align
    int2*  edge   = (int2*)((int*)d_ws + off);          // E int2
    float* xc     = (float*)((int*)d_ws + off + 2 * (size_t)E);  // N*64
    float* ax     = xc + (size_t)N * DIM;               // N*64
    float* hw     = xc;                                 // reuse (xc dead after gather1)
    float* acc2   = ax;                                 // reuse (ax dead after fused_mlp)
    float* outF   = (float*)d_out;

    node_init<<<(N * 64 + 255) / 256, 256, 0, stream>>>(entity, cnt, xc, N);
    hist_kernel<<<1024, 256, 0, stream>>>(dst, cnt, E);
    scan1<<<NB, 1024, 0, stream>>>(cnt, rowptr, bsum, dinv, N);
    scan2<<<1, 1024, 0, stream>>>(bsum, boff, NB);
    scan3<<<NB, 1024, 0, stream>>>(rowptr, boff, N, NB);
    place_kernel<<<2048, 256, 0, stream>>>(src, dst, rowptr, cnt, dinv, edge, E);
    gather64<<<(N * 64 + 255) / 256, 256, 0, stream>>>(rowptr, edge, dinv, xc, ax, N);
    fused_mlp<<<(N + 15) / 16, 256, 0, stream>>>(ax, W1, b1, W2, hw, N);
    gather64<<<(N * 64 + 255) / 256, 256, 0, stream>>>(rowptr, edge, dinv, hw, acc2, N);
    final_kernel<<<(B * 64 + 255) / 256, 256, 0, stream>>>(user, u, iid, acc2, b2, outF, B);
}

// Round 6
// 420.872 us; speedup vs baseline: 4.6055x; 1.2664x over previous
//
#include <hip/hip_runtime.h>
#include <hip/hip_bf16.h>
#include <math.h>

#define DIM 64
#define HID 128

__device__ __forceinline__ float bf2f(unsigned short us) {
    return __uint_as_float(((unsigned)us) << 16);
}
__device__ __forceinline__ unsigned short f2bf(float f) {
    unsigned u = __float_as_uint(f);
    unsigned r = u + 0x7FFFu + ((u >> 16) & 1u);   // round-to-nearest-even
    return (unsigned short)(r >> 16);
}

// ---- node init: xc = bf16(clip_max_norm(entity)); cnt = 0 -------------------
__global__ __launch_bounds__(256) void node_init(const float* __restrict__ emb,
                                                 int* __restrict__ cnt,
                                                 unsigned short* __restrict__ xc,
                                                 int n_nodes) {
    int lane = threadIdx.x & 63;
    int wid = (blockIdx.x * 256 + threadIdx.x) >> 6;
    if (wid >= n_nodes) return;
    float v = emb[(size_t)wid * DIM + lane];
    float s = v * v;
    #pragma unroll
    for (int off = 32; off; off >>= 1) s += __shfl_xor(s, off);
    float sc = fminf(1.0f, 1.0f / (sqrtf(s) + 1e-7f));
    xc[(size_t)wid * DIM + lane] = f2bf(v * sc);
    if (lane == 0) cnt[wid] = 0;
}

// ---- histogram of dst ------------------------------------------------------
__global__ void hist_kernel(const int* __restrict__ dst, int* __restrict__ cnt, int nedges) {
    int i = blockIdx.x * blockDim.x + threadIdx.x;
    int n = gridDim.x * blockDim.x;
    for (int e = i; e < nedges; e += n) atomicAdd(&cnt[dst[e]], 1);
}

// ---- scan phase 1: per-block exclusive scan of cnt; dinv; cnt=0 -------------
__global__ __launch_bounds__(1024) void scan1(int* __restrict__ cnt,
                                              int* __restrict__ rowptr,
                                              int* __restrict__ bsum,
                                              float* __restrict__ dinv,
                                              int N) {
    __shared__ int wsums[16];
    int tid = threadIdx.x, lane = tid & 63, wid = tid >> 6;
    int i = blockIdx.x * 1024 + tid;
    int v = (i < N) ? cnt[i] : 0;
    int x = v;
    #pragma unroll
    for (int off = 1; off < 64; off <<= 1) {
        int y = __shfl_up(x, off, 64);
        if (lane >= off) x += y;
    }
    if (lane == 63) wsums[wid] = x;
    __syncthreads();
    if (wid == 0) {
        int t = (lane < 16) ? wsums[lane] : 0;
        #pragma unroll
        for (int off = 1; off < 16; off <<= 1) {
            int y = __shfl_up(t, off, 64);
            if (lane >= off) t += y;
        }
        if (lane < 16) wsums[lane] = t;
    }
    __syncthreads();
    int woff = wid ? wsums[wid - 1] : 0;
    int excl = woff + x - v;
    if (i < N) {
        rowptr[i] = excl;
        dinv[i] = rsqrtf((float)(1 + v));   // +1 self loop; deg >= 1 always
        cnt[i] = 0;                          // reset as placement cursor
    }
    if (tid == 0) bsum[blockIdx.x] = wsums[15];
}

// ---- scan phase 2: single-block exclusive scan of block sums (NB <= 1024) ---
__global__ __launch_bounds__(1024) void scan2(const int* __restrict__ bsum,
                                              int* __restrict__ boff,
                                              int NB) {
    __shared__ int wsums[16];
    int tid = threadIdx.x, lane = tid & 63, wid = tid >> 6;
    int v = (tid < NB) ? bsum[tid] : 0;
    int x = v;
    #pragma unroll
    for (int off = 1; off < 64; off <<= 1) {
        int y = __shfl_up(x, off, 64);
        if (lane >= off) x += y;
    }
    if (lane == 63) wsums[wid] = x;
    __syncthreads();
    if (wid == 0) {
        int t = (lane < 16) ? wsums[lane] : 0;
        #pragma unroll
        for (int off = 1; off < 16; off <<= 1) {
            int y = __shfl_up(t, off, 64);
            if (lane >= off) t += y;
        }
        if (lane < 16) wsums[lane] = t;
    }
    __syncthreads();
    int woff = wid ? wsums[wid - 1] : 0;
    if (tid < NB) boff[tid] = woff + x - v;
    if (tid == 0) boff[NB] = wsums[15];   // grand total
}

// ---- scan phase 3: add block offsets; finalize rowptr[N] --------------------
__global__ __launch_bounds__(1024) void scan3(int* __restrict__ rowptr,
                                              const int* __restrict__ boff,
                                              int N, int NB) {
    int i = blockIdx.x * 1024 + threadIdx.x;
    if (i < N) rowptr[i] += boff[blockIdx.x];
    if (i == 0) rowptr[N] = boff[NB];
}

// ---- placement: edge[slot] = {src, dinv[s]*dinv[d]} bucketed by dst ---------
__global__ void place_kernel(const int* __restrict__ src, const int* __restrict__ dst,
                             const int* __restrict__ rowptr, int* __restrict__ cnt,
                             const float* __restrict__ dinv,
                             int2* __restrict__ edge, int nedges) {
    int i = blockIdx.x * blockDim.x + threadIdx.x;
    int n = gridDim.x * blockDim.x;
    for (int e = i; e < nedges; e += n) {
        int s = src[e], d = dst[e];
        int slot = rowptr[d] + atomicAdd(&cnt[d], 1);
        edge[slot] = make_int2(s, __float_as_int(dinv[s] * dinv[d]));
    }
}

// ---- CSR gather over bf16 table: ax[d] = xc[d]*dinv^2 + sum xc[s]*w (f32 acc)
__global__ __launch_bounds__(256) void gather_bf16(const int* __restrict__ rowptr,
                                                   const int2* __restrict__ edge,
                                                   const float* __restrict__ dinv,
                                                   const unsigned short* __restrict__ val,
                                                   float* __restrict__ out,
                                                   int n_nodes) {
    int lane = threadIdx.x & 63;
    int node = (blockIdx.x * 256 + threadIdx.x) >> 6;
    if (node >= n_nodes) return;
    int beg = rowptr[node], end = rowptr[node + 1];
    float di = dinv[node];
    float acc = bf2f(val[(size_t)node * DIM + lane]) * (di * di);
    int p = beg;
    for (; p + 3 < end; p += 4) {
        int2 e0 = edge[p], e1 = edge[p + 1], e2 = edge[p + 2], e3 = edge[p + 3];
        float v0 = bf2f(val[(size_t)e0.x * DIM + lane]);
        float v1 = bf2f(val[(size_t)e1.x * DIM + lane]);
        float v2 = bf2f(val[(size_t)e2.x * DIM + lane]);
        float v3 = bf2f(val[(size_t)e3.x * DIM + lane]);
        acc += v0 * __int_as_float(e0.y);
        acc += v1 * __int_as_float(e1.y);
        acc += v2 * __int_as_float(e2.y);
        acc += v3 * __int_as_float(e3.y);
    }
    for (; p < end; ++p) {
        int2 e = edge[p];
        acc += bf2f(val[(size_t)e.x * DIM + lane]) * __int_as_float(e.y);
    }
    out[(size_t)node * DIM + lane] = acc;
}

// ---- fused MLP: hw = relu(ax @ W1 + b1) @ W2, bf16 weights in LDS -----------
// grid-stride over 16-row tiles; weights staged ONCE per block.
__global__ __launch_bounds__(256) void fused_mlp(const float* __restrict__ ax,
                                                 const float* __restrict__ W1,
                                                 const float* __restrict__ b1,
                                                 const float* __restrict__ W2,
                                                 float* __restrict__ hw,
                                                 int n_nodes, int ntiles) {
    __shared__ unsigned int w1u[DIM * HID / 2];   // 16 KB: row d, uint c2 = cols {2c2,2c2+1}
    __shared__ unsigned int w2u[HID * DIM / 2];   // 16 KB
    __shared__ float xl[16 * DIM];                // 4 KB
    __shared__ float hl[16 * HID];                // 8 KB  -> total 44 KB
    int tid = threadIdx.x;
    for (int idx = tid; idx < DIM * HID / 2; idx += 256) {
        float2 wf = *(const float2*)&W1[idx * 2];
        w1u[idx] = (unsigned)f2bf(wf.x) | ((unsigned)f2bf(wf.y) << 16);
    }
    for (int idx = tid; idx < HID * DIM / 2; idx += 256) {
        float2 wf = *(const float2*)&W2[idx * 2];
        w2u[idx] = (unsigned)f2bf(wf.x) | ((unsigned)f2bf(wf.y) << 16);
    }
    int hq = tid & 31;          // stage-1 column quad (128 cols = 32 quads)
    int rs = tid >> 5;          // stage-1 row pair base: rows rs, rs+8
    int oq = tid & 15;          // stage-2 column quad (64 cols = 16 quads)
    int rs2 = tid >> 4;         // stage-2 row 0..15
    float4 bq = *(const float4*)&b1[hq * 4];
    __syncthreads();

    for (int t = blockIdx.x; t < ntiles; t += gridDim.x) {
        int row0 = t * 16;
        __syncthreads();   // prev tile's stage2 done before xl/hl overwrite
        {
            int r = tid >> 4, c = (tid & 15) * 4;
            int n = row0 + r;
            float4 v = {0.f, 0.f, 0.f, 0.f};
            if (n < n_nodes) v = *(const float4*)&ax[(size_t)n * DIM + c];
            *(float4*)&xl[r * DIM + c] = v;
        }
        __syncthreads();
        // stage 1: hl[16][128] = relu(xl @ W1 + b1); 2 rows per weight read
        {
            float4 a0 = {0.f, 0.f, 0.f, 0.f};
            float4 a1 = {0.f, 0.f, 0.f, 0.f};
            #pragma unroll 8
            for (int d = 0; d < DIM; ++d) {
                uint2 w = *(const uint2*)&w1u[d * 64 + hq * 2];
                float w0 = __uint_as_float(w.x << 16);
                float w1f = __uint_as_float(w.x & 0xFFFF0000u);
                float w2f = __uint_as_float(w.y << 16);
                float w3f = __uint_as_float(w.y & 0xFFFF0000u);
                float x0 = xl[rs * DIM + d];
                float x1 = xl[(rs + 8) * DIM + d];
                a0.x += x0 * w0; a0.y += x0 * w1f; a0.z += x0 * w2f; a0.w += x0 * w3f;
                a1.x += x1 * w0; a1.y += x1 * w1f; a1.z += x1 * w2f; a1.w += x1 * w3f;
            }
            a0.x = fmaxf(a0.x + bq.x, 0.f); a0.y = fmaxf(a0.y + bq.y, 0.f);
            a0.z = fmaxf(a0.z + bq.z, 0.f); a0.w = fmaxf(a0.w + bq.w, 0.f);
            a1.x = fmaxf(a1.x + bq.x, 0.f); a1.y = fmaxf(a1.y + bq.y, 0.f);
            a1.z = fmaxf(a1.z + bq.z, 0.f); a1.w = fmaxf(a1.w + bq.w, 0.f);
            *(float4*)&hl[rs * HID + hq * 4] = a0;
            *(float4*)&hl[(rs + 8) * HID + hq * 4] = a1;
        }
        __syncthreads();
        // stage 2: hw[16][64] = hl @ W2
        {
            int n = row0 + rs2;
            float4 acc = {0.f, 0.f, 0.f, 0.f};
            #pragma unroll 8
            for (int d = 0; d < HID; ++d) {
                uint2 w = *(const uint2*)&w2u[d * 32 + oq * 2];
                float w0 = __uint_as_float(w.x << 16);
                float w1f = __uint_as_float(w.x & 0xFFFF0000u);
                float w2f = __uint_as_float(w.y << 16);
                float w3f = __uint_as_float(w.y & 0xFFFF0000u);
                float h = hl[rs2 * HID + d];
                acc.x += h * w0; acc.y += h * w1f; acc.z += h * w2f; acc.w += h * w3f;
            }
            if (n < n_nodes) *(float4*)&hw[(size_t)n * DIM + oq * 4] = acc;
        }
    }
}

// ---- fused layer-2 gather + final, batch-wide only --------------------------
// item = gather(hw)[ii] + b2 ; logit = sigmoid(<clip(user)[uu], item>)
__global__ __launch_bounds__(256) void item_final(const int* __restrict__ rowptr,
                                                  const int2* __restrict__ edge,
                                                  const float* __restrict__ dinv,
                                                  const float* __restrict__ hw,
                                                  const float* __restrict__ b2,
                                                  const float* __restrict__ user_emb,
                                                  const int* __restrict__ u,
                                                  const int* __restrict__ iid,
                                                  float* __restrict__ out,
                                                  int batch) {
    int lane = threadIdx.x & 63;
    int b = (blockIdx.x * 256 + threadIdx.x) >> 6;
    if (b >= batch) return;
    int ii = iid[b], uu = u[b];
    float uv = user_emb[(size_t)uu * DIM + lane];
    float s = uv * uv;
    #pragma unroll
    for (int off = 32; off; off >>= 1) s += __shfl_xor(s, off);
    float sc = fminf(1.0f, 1.0f / (sqrtf(s) + 1e-7f));
    float di = dinv[ii];
    float acc = hw[(size_t)ii * DIM + lane] * (di * di);
    int beg = rowptr[ii], end = rowptr[ii + 1];
    int p = beg;
    for (; p + 1 < end; p += 2) {
        int2 e0 = edge[p], e1 = edge[p + 1];
        float v0 = hw[(size_t)e0.x * DIM + lane];
        float v1 = hw[(size_t)e1.x * DIM + lane];
        acc += v0 * __int_as_float(e0.y) + v1 * __int_as_float(e1.y);
    }
    if (p < end) {
        int2 e = edge[p];
        acc += hw[(size_t)e.x * DIM + lane] * __int_as_float(e.y);
    }
    float item = acc + b2[lane];
    float dot = uv * sc * item;
    #pragma unroll
    for (int off = 32; off; off >>= 1) dot += __shfl_xor(dot, off);
    if (lane == 0) out[b] = 1.0f / (1.0f + expf(-dot));
}

extern "C" void kernel_launch(void* const* d_in, const int* in_sizes, int n_in,
                              void* d_out, int out_size, void* d_ws, size_t ws_size,
                              hipStream_t stream) {
    const float* entity = (const float*)d_in[0];
    const float* user   = (const float*)d_in[1];
    const float* W1     = (const float*)d_in[2];
    const float* b1     = (const float*)d_in[3];
    const float* W2     = (const float*)d_in[4];
    const float* b2     = (const float*)d_in[5];
    const int*   u      = (const int*)d_in[6];
    const int*   iid    = (const int*)d_in[7];
    const int*   eidx   = (const int*)d_in[8];

    int N = in_sizes[0] / DIM;      // 100000
    int B = in_sizes[6];            // 8192
    int E = in_sizes[8] / 2;        // 1600000
    const int* src = eidx;
    const int* dst = eidx + E;
    int NB = (N + 1023) / 1024;     // 98 (<= 1024)
    int ntiles = (N + 15) / 16;

    // workspace layout (4-byte units; edge needs 8B alignment)
    int*   cnt    = (int*)d_ws;                          // N
    int*   rowptr = cnt + N;                             // N+1
    int*   bsum   = rowptr + N + 1;                      // NB
    int*   boff   = bsum + NB;                           // NB+1
    float* dinv   = (float*)(boff + NB + 1);             // N
    size_t off4   = (size_t)(3 * N + 2 * NB + 2);
    off4 = (off4 + 1) & ~(size_t)1;                      // 8B align
    int2*  edge   = (int2*)((int*)d_ws + off4);          // E int2
    unsigned short* xc = (unsigned short*)((int*)d_ws + off4 + 2 * (size_t)E);  // N*64 bf16
    float* ax     = (float*)((int*)d_ws + off4 + 2 * (size_t)E + 32 * (size_t)N); // N*64 f32
    float* hw     = ax + (size_t)N * DIM;                // N*64 f32
    float* outF   = (float*)d_out;

    node_init<<<(N * 64 + 255) / 256, 256, 0, stream>>>(entity, cnt, xc, N);
    hist_kernel<<<1024, 256, 0, stream>>>(dst, cnt, E);
    scan1<<<NB, 1024, 0, stream>>>(cnt, rowptr, bsum, dinv, N);
    scan2<<<1, 1024, 0, stream>>>(bsum, boff, NB);
    scan3<<<NB, 1024, 0, stream>>>(rowptr, boff, N, NB);
    place_kernel<<<2048, 256, 0, stream>>>(src, dst, rowptr, cnt, dinv, edge, E);
    gather_bf16<<<(N * 64 + 255) / 256, 256, 0, stream>>>(rowptr, edge, dinv, xc, ax, N);
    fused_mlp<<<768, 256, 0, stream>>>(ax, W1, b1, W2, hw, N, ntiles);
    item_final<<<(B * 64 + 255) / 256, 256, 0, stream>>>(rowptr, edge, dinv, hw, b2, user, u, iid, outF, B);
}

// Round 7
// 404.381 us; speedup vs baseline: 4.7933x; 1.0408x over previous
//
#include <hip/hip_runtime.h>
#include <hip/hip_bf16.h>
#include <math.h>

#define DIM 64
#define HID 128

typedef __attribute__((ext_vector_type(8))) short bf16x8;
typedef __attribute__((ext_vector_type(4))) float f32x4;

__device__ __forceinline__ float bf2f(unsigned short us) {
    return __uint_as_float(((unsigned)us) << 16);
}
__device__ __forceinline__ unsigned short f2bf(float f) {
    unsigned u = __float_as_uint(f);
    unsigned r = u + 0x7FFFu + ((u >> 16) & 1u);   // round-to-nearest-even
    return (unsigned short)(r >> 16);
}

// ---- zero the degree counters ----------------------------------------------
__global__ __launch_bounds__(1024) void zero_cnt(int* __restrict__ cnt, int N) {
    int i = blockIdx.x * 1024 + threadIdx.x;
    if (i < N) cnt[i] = 0;
}

// ---- histogram of dst ------------------------------------------------------
__global__ void hist_kernel(const int* __restrict__ dst, int* __restrict__ cnt, int nedges) {
    int i = blockIdx.x * blockDim.x + threadIdx.x;
    int n = gridDim.x * blockDim.x;
    for (int e = i; e < nedges; e += n) atomicAdd(&cnt[dst[e]], 1);
}

// ---- scan phase 1: per-block exclusive scan of cnt; dinv; cnt=0 -------------
__global__ __launch_bounds__(1024) void scan1(int* __restrict__ cnt,
                                              int* __restrict__ rowptr,
                                              int* __restrict__ bsum,
                                              float* __restrict__ dinv,
                                              int N) {
    __shared__ int wsums[16];
    int tid = threadIdx.x, lane = tid & 63, wid = tid >> 6;
    int i = blockIdx.x * 1024 + tid;
    int v = (i < N) ? cnt[i] : 0;
    int x = v;
    #pragma unroll
    for (int off = 1; off < 64; off <<= 1) {
        int y = __shfl_up(x, off, 64);
        if (lane >= off) x += y;
    }
    if (lane == 63) wsums[wid] = x;
    __syncthreads();
    if (wid == 0) {
        int t = (lane < 16) ? wsums[lane] : 0;
        #pragma unroll
        for (int off = 1; off < 16; off <<= 1) {
            int y = __shfl_up(t, off, 64);
            if (lane >= off) t += y;
        }
        if (lane < 16) wsums[lane] = t;
    }
    __syncthreads();
    int woff = wid ? wsums[wid - 1] : 0;
    int excl = woff + x - v;
    if (i < N) {
        rowptr[i] = excl;
        dinv[i] = rsqrtf((float)(1 + v));   // +1 self loop; deg >= 1 always
        cnt[i] = 0;                          // reset as placement cursor
    }
    if (tid == 0) bsum[blockIdx.x] = wsums[15];
}

// ---- scan phase 2: single-block exclusive scan of block sums (NB <= 1024) ---
__global__ __launch_bounds__(1024) void scan2(const int* __restrict__ bsum,
                                              int* __restrict__ boff,
                                              int NB) {
    __shared__ int wsums[16];
    int tid = threadIdx.x, lane = tid & 63, wid = tid >> 6;
    int v = (tid < NB) ? bsum[tid] : 0;
    int x = v;
    #pragma unroll
    for (int off = 1; off < 64; off <<= 1) {
        int y = __shfl_up(x, off, 64);
        if (lane >= off) x += y;
    }
    if (lane == 63) wsums[wid] = x;
    __syncthreads();
    if (wid == 0) {
        int t = (lane < 16) ? wsums[lane] : 0;
        #pragma unroll
        for (int off = 1; off < 16; off <<= 1) {
            int y = __shfl_up(t, off, 64);
            if (lane >= off) t += y;
        }
        if (lane < 16) wsums[lane] = t;
    }
    __syncthreads();
    int woff = wid ? wsums[wid - 1] : 0;
    if (tid < NB) boff[tid] = woff + x - v;
    if (tid == 0) boff[NB] = wsums[15];   // grand total
}

// ---- scan phase 3: add block offsets; finalize rowptr[N] --------------------
__global__ __launch_bounds__(1024) void scan3(int* __restrict__ rowptr,
                                              const int* __restrict__ boff,
                                              int N, int NB) {
    int i = blockIdx.x * 1024 + threadIdx.x;
    if (i < N) rowptr[i] += boff[blockIdx.x];
    if (i == 0) rowptr[N] = boff[NB];
}

// ---- node init: xv = bf16(clip_max_norm(x) * dinv) (dinv[s] folded in) ------
__global__ __launch_bounds__(256) void node_init(const float* __restrict__ emb,
                                                 const float* __restrict__ dinv,
                                                 unsigned short* __restrict__ xv,
                                                 int n_nodes) {
    int lane = threadIdx.x & 63;
    int wid = (blockIdx.x * 256 + threadIdx.x) >> 6;
    if (wid >= n_nodes) return;
    float v = emb[(size_t)wid * DIM + lane];
    float s = v * v;
    #pragma unroll
    for (int off = 32; off; off >>= 1) s += __shfl_xor(s, off);
    float sc = fminf(1.0f, 1.0f / (sqrtf(s) + 1e-7f));
    xv[(size_t)wid * DIM + lane] = f2bf(v * sc * dinv[wid]);
}

// ---- placement: srcs[slot] = src, bucketed by dst (no weight needed) --------
__global__ void place_kernel(const int* __restrict__ src, const int* __restrict__ dst,
                             const int* __restrict__ rowptr, int* __restrict__ cnt,
                             int* __restrict__ srcs, int nedges) {
    int i = blockIdx.x * blockDim.x + threadIdx.x;
    int n = gridDim.x * blockDim.x;
    for (int e = i; e < nedges; e += n) {
        int s = src[e], d = dst[e];
        int slot = rowptr[d] + atomicAdd(&cnt[d], 1);
        srcs[slot] = s;
    }
}

// ---- gather1: ax[d] = bf16( dinv[d] * (xv[d] + sum_e xv[src_e]) ) -----------
__global__ __launch_bounds__(256) void gather_ax(const int* __restrict__ rowptr,
                                                 const int* __restrict__ srcs,
                                                 const float* __restrict__ dinv,
                                                 const unsigned short* __restrict__ xv,
                                                 unsigned short* __restrict__ ax,
                                                 int n_nodes) {
    int lane = threadIdx.x & 63;
    int node = (blockIdx.x * 256 + threadIdx.x) >> 6;
    if (node >= n_nodes) return;
    int beg = rowptr[node], end = rowptr[node + 1];
    float acc = bf2f(xv[(size_t)node * DIM + lane]);
    int p = beg;
    for (; p + 3 < end; p += 4) {
        int s0 = srcs[p], s1 = srcs[p + 1], s2 = srcs[p + 2], s3 = srcs[p + 3];
        acc += bf2f(xv[(size_t)s0 * DIM + lane]);
        acc += bf2f(xv[(size_t)s1 * DIM + lane]);
        acc += bf2f(xv[(size_t)s2 * DIM + lane]);
        acc += bf2f(xv[(size_t)s3 * DIM + lane]);
    }
    for (; p < end; ++p) acc += bf2f(xv[(size_t)srcs[p] * DIM + lane]);
    ax[(size_t)node * DIM + lane] = f2bf(dinv[node] * acc);
}

// ---- MFMA fused MLP: hv = (relu(ax @ W1 + b1) @ W2) * dinv ------------------
// 32-row tiles, 4 waves/block; wave w owns cols [w*32,w*32+32) (s1) / [w*16..) (s2).
// LDS rows padded +8 bf16 -> row stride odd multiple of 16B -> conflict-free b128.
__global__ __launch_bounds__(256) void mfma_mlp(const unsigned short* __restrict__ ax,
                                                const float* __restrict__ W1,
                                                const float* __restrict__ b1,
                                                const float* __restrict__ W2,
                                                const float* __restrict__ dinv,
                                                float* __restrict__ hv,
                                                int n_nodes, int ntiles) {
    __shared__ unsigned short w1t[128][72];   // W1T[n][k] = W1[k][n], 18 KB
    __shared__ unsigned short w2t[64][136];   // W2T[n][k] = W2[k][n], 17 KB
    __shared__ unsigned short axl[32][72];    // A rows, 4.5 KB
    __shared__ unsigned short hL[32][136];    // H rows, 8.5 KB
    __shared__ float b1l[128];
    int tid = threadIdx.x;
    for (int idx = tid; idx < DIM * HID; idx += 256) {
        int k = idx >> 7, n = idx & 127;
        w1t[n][k] = f2bf(W1[idx]);
    }
    for (int idx = tid; idx < HID * DIM; idx += 256) {
        int k = idx >> 6, n = idx & 63;
        w2t[n][k] = f2bf(W2[idx]);
    }
    if (tid < 128) b1l[tid] = b1[tid];
    int lane = tid & 63;
    int w = tid >> 6;        // wave 0..3
    int l15 = lane & 15;
    int lq = lane >> 4;      // 0..3
    __syncthreads();

    for (int t = blockIdx.x; t < ntiles; t += gridDim.x) {
        int row0 = t * 32;
        {   // load ax tile: 32 rows x 64 bf16; thread -> 16B
            int r = tid >> 3, c8 = (tid & 7) * 8;
            int n = row0 + r;
            uint4 v = {0u, 0u, 0u, 0u};
            if (n < n_nodes) v = *(const uint4*)&ax[(size_t)n * DIM + c8];
            *(uint4*)&axl[r][c8] = v;
        }
        __syncthreads();
        // stage 1: C1[32x128] = A @ W1
        f32x4 acc00 = {}, acc01 = {}, acc10 = {}, acc11 = {};
        #pragma unroll
        for (int kk = 0; kk < 2; ++kk) {
            int kb = kk * 32 + lq * 8;
            bf16x8 a0 = *(const bf16x8*)&axl[l15][kb];
            bf16x8 a1 = *(const bf16x8*)&axl[16 + l15][kb];
            bf16x8 b0 = *(const bf16x8*)&w1t[w * 32 + l15][kb];
            bf16x8 b1v = *(const bf16x8*)&w1t[w * 32 + 16 + l15][kb];
            acc00 = __builtin_amdgcn_mfma_f32_16x16x32_bf16(a0, b0, acc00, 0, 0, 0);
            acc01 = __builtin_amdgcn_mfma_f32_16x16x32_bf16(a0, b1v, acc01, 0, 0, 0);
            acc10 = __builtin_amdgcn_mfma_f32_16x16x32_bf16(a1, b0, acc10, 0, 0, 0);
            acc11 = __builtin_amdgcn_mfma_f32_16x16x32_bf16(a1, b1v, acc11, 0, 0, 0);
        }
        // relu + bias -> hL (bf16). C layout: col = lane&15, row = lq*4 + r
        {
            int c0 = w * 32 + l15, c1 = w * 32 + 16 + l15;
            float bb0 = b1l[c0], bb1 = b1l[c1];
            #pragma unroll
            for (int r = 0; r < 4; ++r) {
                hL[lq * 4 + r][c0]      = f2bf(fmaxf(acc00[r] + bb0, 0.f));
                hL[lq * 4 + r][c1]      = f2bf(fmaxf(acc01[r] + bb1, 0.f));
                hL[16 + lq * 4 + r][c0] = f2bf(fmaxf(acc10[r] + bb0, 0.f));
                hL[16 + lq * 4 + r][c1] = f2bf(fmaxf(acc11[r] + bb1, 0.f));
            }
        }
        __syncthreads();
        // stage 2: C2[32x64] = H @ W2; wave w owns cols [w*16, w*16+16)
        f32x4 o0 = {}, o1 = {};
        #pragma unroll
        for (int kk = 0; kk < 4; ++kk) {
            int kb = kk * 32 + lq * 8;
            bf16x8 h0 = *(const bf16x8*)&hL[l15][kb];
            bf16x8 h1 = *(const bf16x8*)&hL[16 + l15][kb];
            bf16x8 bw = *(const bf16x8*)&w2t[w * 16 + l15][kb];
            o0 = __builtin_amdgcn_mfma_f32_16x16x32_bf16(h0, bw, o0, 0, 0, 0);
            o1 = __builtin_amdgcn_mfma_f32_16x16x32_bf16(h1, bw, o1, 0, 0, 0);
        }
        #pragma unroll
        for (int r = 0; r < 4; ++r) {
            int row = row0 + lq * 4 + r;
            if (row < n_nodes)
                hv[(size_t)row * DIM + w * 16 + l15] = o0[r] * dinv[row];
            int row2 = row + 16;
            if (row2 < n_nodes)
                hv[(size_t)row2 * DIM + w * 16 + l15] = o1[r] * dinv[row2];
        }
        __syncthreads();   // protect axl/hL before next tile
    }
}

// ---- fused layer-2 gather + final, batch-wide only --------------------------
// conv2[ii] = dinv[ii]*(hv[ii] + sum_e hv[src_e]) + b2 ; logit = sigmoid(dot)
__global__ __launch_bounds__(256) void item_final(const int* __restrict__ rowptr,
                                                  const int* __restrict__ srcs,
                                                  const float* __restrict__ dinv,
                                                  const float* __restrict__ hv,
                                                  const float* __restrict__ b2,
                                                  const float* __restrict__ user_emb,
                                                  const int* __restrict__ u,
                                                  const int* __restrict__ iid,
                                                  float* __restrict__ out,
                                                  int batch) {
    int lane = threadIdx.x & 63;
    int b = (blockIdx.x * 256 + threadIdx.x) >> 6;
    if (b >= batch) return;
    int ii = iid[b], uu = u[b];
    float uv = user_emb[(size_t)uu * DIM + lane];
    float s = uv * uv;
    #pragma unroll
    for (int off = 32; off; off >>= 1) s += __shfl_xor(s, off);
    float sc = fminf(1.0f, 1.0f / (sqrtf(s) + 1e-7f));
    float acc = hv[(size_t)ii * DIM + lane];
    int beg = rowptr[ii], end = rowptr[ii + 1];
    int p = beg;
    for (; p + 1 < end; p += 2) {
        int s0 = srcs[p], s1 = srcs[p + 1];
        acc += hv[(size_t)s0 * DIM + lane] + hv[(size_t)s1 * DIM + lane];
    }
    if (p < end) acc += hv[(size_t)srcs[p] * DIM + lane];
    float item = dinv[ii] * acc + b2[lane];
    float dot = uv * sc * item;
    #pragma unroll
    for (int off = 32; off; off >>= 1) dot += __shfl_xor(dot, off);
    if (lane == 0) out[b] = 1.0f / (1.0f + expf(-dot));
}

extern "C" void kernel_launch(void* const* d_in, const int* in_sizes, int n_in,
                              void* d_out, int out_size, void* d_ws, size_t ws_size,
                              hipStream_t stream) {
    const float* entity = (const float*)d_in[0];
    const float* user   = (const float*)d_in[1];
    const float* W1     = (const float*)d_in[2];
    const float* b1     = (const float*)d_in[3];
    const float* W2     = (const float*)d_in[4];
    const float* b2     = (const float*)d_in[5];
    const int*   u      = (const int*)d_in[6];
    const int*   iid    = (const int*)d_in[7];
    const int*   eidx   = (const int*)d_in[8];

    int N = in_sizes[0] / DIM;      // 100000
    int B = in_sizes[6];            // 8192
    int E = in_sizes[8] / 2;        // 1600000
    const int* src = eidx;
    const int* dst = eidx + E;
    int NB = (N + 1023) / 1024;     // 98 (<= 1024)
    int ntiles = (N + 31) / 32;     // 3125

    // workspace layout, 16B-aligned segments
    char* p = (char*)d_ws;
    auto alloc = [&](size_t bytes) { char* r = p; p += (bytes + 15) & ~(size_t)15; return r; };
    int*   cnt    = (int*)alloc((size_t)N * 4);
    int*   rowptr = (int*)alloc((size_t)(N + 1) * 4);
    int*   bsum   = (int*)alloc((size_t)NB * 4);
    int*   boff   = (int*)alloc((size_t)(NB + 1) * 4);
    float* dinv   = (float*)alloc((size_t)N * 4);
    int*   srcs   = (int*)alloc((size_t)E * 4);
    unsigned short* xv = (unsigned short*)alloc((size_t)N * DIM * 2);
    unsigned short* ax = (unsigned short*)alloc((size_t)N * DIM * 2);
    float* hv     = (float*)alloc((size_t)N * DIM * 4);
    float* outF   = (float*)d_out;

    zero_cnt<<<NB, 1024, 0, stream>>>(cnt, N);
    hist_kernel<<<1024, 256, 0, stream>>>(dst, cnt, E);
    scan1<<<NB, 1024, 0, stream>>>(cnt, rowptr, bsum, dinv, N);
    scan2<<<1, 1024, 0, stream>>>(bsum, boff, NB);
    scan3<<<NB, 1024, 0, stream>>>(rowptr, boff, N, NB);
    node_init<<<(N * 64 + 255) / 256, 256, 0, stream>>>(entity, dinv, xv, N);
    place_kernel<<<2048, 256, 0, stream>>>(src, dst, rowptr, cnt, srcs, E);
    gather_ax<<<(N * 64 + 255) / 256, 256, 0, stream>>>(rowptr, srcs, dinv, xv, ax, N);
    mfma_mlp<<<512, 256, 0, stream>>>(ax, W1, b1, W2, dinv, hv, N, ntiles);
    item_final<<<(B * 64 + 255) / 256, 256, 0, stream>>>(rowptr, srcs, dinv, hv, b2, user, u, iid, outF, B);
}

// Round 8
// 361.337 us; speedup vs baseline: 5.3644x; 1.1191x over previous
//
#include <hip/hip_runtime.h>
#include <hip/hip_bf16.h>
#include <math.h>

#define DIM 64
#define HID 128
#define NRANGE 8

typedef __attribute__((ext_vector_type(8))) short bf16x8;
typedef __attribute__((ext_vector_type(4))) float f32x4;

__device__ __forceinline__ float bf2f(unsigned short us) {
    return __uint_as_float(((unsigned)us) << 16);
}
__device__ __forceinline__ unsigned short f2bf(float f) {
    unsigned u = __float_as_uint(f);
    unsigned r = u + 0x7FFFu + ((u >> 16) & 1u);   // round-to-nearest-even
    return (unsigned short)(r >> 16);
}

// ---- zero the degree counters ----------------------------------------------
__global__ __launch_bounds__(1024) void zero_cnt(int* __restrict__ cnt, int N) {
    int i = blockIdx.x * 1024 + threadIdx.x;
    if (i < N) cnt[i] = 0;
}

// ---- histogram of dst ------------------------------------------------------
__global__ void hist_kernel(const int* __restrict__ dst, int* __restrict__ cnt, int nedges) {
    int i = blockIdx.x * blockDim.x + threadIdx.x;
    int n = gridDim.x * blockDim.x;
    for (int e = i; e < nedges; e += n) atomicAdd(&cnt[dst[e]], 1);
}

// ---- scan phase 1: per-block exclusive scan of cnt; dinv; cnt=0 -------------
__global__ __launch_bounds__(1024) void scan1(int* __restrict__ cnt,
                                              int* __restrict__ rowptr,
                                              int* __restrict__ bsum,
                                              float* __restrict__ dinv,
                                              int N) {
    __shared__ int wsums[16];
    int tid = threadIdx.x, lane = tid & 63, wid = tid >> 6;
    int i = blockIdx.x * 1024 + tid;
    int v = (i < N) ? cnt[i] : 0;
    int x = v;
    #pragma unroll
    for (int off = 1; off < 64; off <<= 1) {
        int y = __shfl_up(x, off, 64);
        if (lane >= off) x += y;
    }
    if (lane == 63) wsums[wid] = x;
    __syncthreads();
    if (wid == 0) {
        int t = (lane < 16) ? wsums[lane] : 0;
        #pragma unroll
        for (int off = 1; off < 16; off <<= 1) {
            int y = __shfl_up(t, off, 64);
            if (lane >= off) t += y;
        }
        if (lane < 16) wsums[lane] = t;
    }
    __syncthreads();
    int woff = wid ? wsums[wid - 1] : 0;
    int excl = woff + x - v;
    if (i < N) {
        rowptr[i] = excl;
        dinv[i] = rsqrtf((float)(1 + v));   // +1 self loop; deg >= 1 always
        cnt[i] = 0;                          // reset as placement cursor
    }
    if (tid == 0) bsum[blockIdx.x] = wsums[15];
}

// ---- scan phase 2: single-block exclusive scan of block sums (NB <= 1024) ---
__global__ __launch_bounds__(1024) void scan2(const int* __restrict__ bsum,
                                              int* __restrict__ boff,
                                              int NB) {
    __shared__ int wsums[16];
    int tid = threadIdx.x, lane = tid & 63, wid = tid >> 6;
    int v = (tid < NB) ? bsum[tid] : 0;
    int x = v;
    #pragma unroll
    for (int off = 1; off < 64; off <<= 1) {
        int y = __shfl_up(x, off, 64);
        if (lane >= off) x += y;
    }
    if (lane == 63) wsums[wid] = x;
    __syncthreads();
    if (wid == 0) {
        int t = (lane < 16) ? wsums[lane] : 0;
        #pragma unroll
        for (int off = 1; off < 16; off <<= 1) {
            int y = __shfl_up(t, off, 64);
            if (lane >= off) t += y;
        }
        if (lane < 16) wsums[lane] = t;
    }
    __syncthreads();
    int woff = wid ? wsums[wid - 1] : 0;
    if (tid < NB) boff[tid] = woff + x - v;
    if (tid == 0) boff[NB] = wsums[15];   // grand total
}

// ---- scan phase 3: add block offsets; finalize rowptr[N] --------------------
__global__ __launch_bounds__(1024) void scan3(int* __restrict__ rowptr,
                                              const int* __restrict__ boff,
                                              int N, int NB) {
    int i = blockIdx.x * 1024 + threadIdx.x;
    if (i < N) rowptr[i] += boff[blockIdx.x];
    if (i == 0) rowptr[N] = boff[NB];
}

// ---- node init: xv = bf16(clip_max_norm(x) * dinv) (dinv[s] folded in) ------
__global__ __launch_bounds__(256) void node_init(const float* __restrict__ emb,
                                                 const float* __restrict__ dinv,
                                                 unsigned short* __restrict__ xv,
                                                 int n_nodes) {
    int lane = threadIdx.x & 63;
    int wid = (blockIdx.x * 256 + threadIdx.x) >> 6;
    if (wid >= n_nodes) return;
    float v = emb[(size_t)wid * DIM + lane];
    float s = v * v;
    #pragma unroll
    for (int off = 32; off; off >>= 1) s += __shfl_xor(s, off);
    float sc = fminf(1.0f, 1.0f / (sqrtf(s) + 1e-7f));
    xv[(size_t)wid * DIM + lane] = f2bf(v * sc * dinv[wid]);
}

// ---- placement, dst-range partitioned (8 ranges ~ 8 XCDs) -------------------
// block r=blockIdx&7 handles only dst in [r*rsize,(r+1)*rsize): write window
// 0.8 MB fits per-XCD L2 -> lines absorb all ~16 sibling writes before evict.
__global__ __launch_bounds__(256) void place_kernel(const int* __restrict__ src,
                                                    const int* __restrict__ dst,
                                                    const int* __restrict__ rowptr,
                                                    int* __restrict__ cnt,
                                                    int* __restrict__ srcs,
                                                    int nedges, int rsize) {
    int r = blockIdx.x & (NRANGE - 1);
    int lo = r * rsize, hi = lo + rsize;
    int tid = (blockIdx.x >> 3) * 256 + threadIdx.x;
    int stride = (gridDim.x >> 3) * 256;
    for (int e = tid; e < nedges; e += stride) {
        int d = dst[e];
        if (d < lo || d >= hi) continue;
        int slot = rowptr[d] + atomicAdd(&cnt[d], 1);
        srcs[slot] = src[e];
    }
}

// ---- gather1: ax[d] = bf16( dinv[d] * (xv[d] + sum_e xv[src_e]) ) -----------
// paired edges: lanes 0-31 = edge p (dims as bf16x2), lanes 32-63 = edge p+1.
__global__ __launch_bounds__(256) void gather_ax(const int* __restrict__ rowptr,
                                                 const int* __restrict__ srcs,
                                                 const float* __restrict__ dinv,
                                                 const unsigned* __restrict__ xv32,
                                                 unsigned* __restrict__ ax32,
                                                 int n_nodes) {
    int lane = threadIdx.x & 63;
    int node = (blockIdx.x * 256 + threadIdx.x) >> 6;
    if (node >= n_nodes) return;
    int half = lane >> 5;
    int li = lane & 31;
    int beg = rowptr[node], end = rowptr[node + 1];
    float a0 = 0.f, a1 = 0.f;
    if (half == 0) {   // self term
        unsigned v = xv32[(size_t)node * 32 + li];
        a0 += bf2f((unsigned short)v);
        a1 += bf2f((unsigned short)(v >> 16));
    }
    int p = beg + half;
    for (; p + 2 < end; p += 4) {   // 2 edges per half in flight
        int s0 = srcs[p], s1 = srcs[p + 2];
        unsigned v0 = xv32[(size_t)s0 * 32 + li];
        unsigned v1 = xv32[(size_t)s1 * 32 + li];
        a0 += bf2f((unsigned short)v0) + bf2f((unsigned short)v1);
        a1 += bf2f((unsigned short)(v0 >> 16)) + bf2f((unsigned short)(v1 >> 16));
    }
    for (; p < end; p += 2) {
        int s = srcs[p];
        unsigned v = xv32[(size_t)s * 32 + li];
        a0 += bf2f((unsigned short)v);
        a1 += bf2f((unsigned short)(v >> 16));
    }
    a0 += __shfl_xor(a0, 32);
    a1 += __shfl_xor(a1, 32);
    if (half == 0) {
        float dn = dinv[node];
        ax32[(size_t)node * 32 + li] =
            (unsigned)f2bf(a0 * dn) | ((unsigned)f2bf(a1 * dn) << 16);
    }
}

// ---- MFMA fused MLP: hv = (relu(ax @ W1 + b1) @ W2) * dinv ------------------
__global__ __launch_bounds__(256) void mfma_mlp(const unsigned short* __restrict__ ax,
                                                const float* __restrict__ W1,
                                                const float* __restrict__ b1,
                                                const float* __restrict__ W2,
                                                const float* __restrict__ dinv,
                                                float* __restrict__ hv,
                                                int n_nodes, int ntiles) {
    __shared__ unsigned short w1t[128][72];   // W1T[n][k] = W1[k][n]
    __shared__ unsigned short w2t[64][136];   // W2T[n][k] = W2[k][n]
    __shared__ unsigned short axl[32][72];
    __shared__ unsigned short hL[32][136];
    __shared__ float b1l[128];
    int tid = threadIdx.x;
    for (int idx = tid; idx < DIM * HID; idx += 256) {
        int k = idx >> 7, n = idx & 127;
        w1t[n][k] = f2bf(W1[idx]);
    }
    for (int idx = tid; idx < HID * DIM; idx += 256) {
        int k = idx >> 6, n = idx & 63;
        w2t[n][k] = f2bf(W2[idx]);
    }
    if (tid < 128) b1l[tid] = b1[tid];
    int lane = tid & 63;
    int w = tid >> 6;
    int l15 = lane & 15;
    int lq = lane >> 4;
    __syncthreads();

    for (int t = blockIdx.x; t < ntiles; t += gridDim.x) {
        int row0 = t * 32;
        {
            int r = tid >> 3, c8 = (tid & 7) * 8;
            int n = row0 + r;
            uint4 v = {0u, 0u, 0u, 0u};
            if (n < n_nodes) v = *(const uint4*)&ax[(size_t)n * DIM + c8];
            *(uint4*)&axl[r][c8] = v;
        }
        __syncthreads();
        f32x4 acc00 = {}, acc01 = {}, acc10 = {}, acc11 = {};
        #pragma unroll
        for (int kk = 0; kk < 2; ++kk) {
            int kb = kk * 32 + lq * 8;
            bf16x8 a0 = *(const bf16x8*)&axl[l15][kb];
            bf16x8 a1 = *(const bf16x8*)&axl[16 + l15][kb];
            bf16x8 b0 = *(const bf16x8*)&w1t[w * 32 + l15][kb];
            bf16x8 b1v = *(const bf16x8*)&w1t[w * 32 + 16 + l15][kb];
            acc00 = __builtin_amdgcn_mfma_f32_16x16x32_bf16(a0, b0, acc00, 0, 0, 0);
            acc01 = __builtin_amdgcn_mfma_f32_16x16x32_bf16(a0, b1v, acc01, 0, 0, 0);
            acc10 = __builtin_amdgcn_mfma_f32_16x16x32_bf16(a1, b0, acc10, 0, 0, 0);
            acc11 = __builtin_amdgcn_mfma_f32_16x16x32_bf16(a1, b1v, acc11, 0, 0, 0);
        }
        {
            int c0 = w * 32 + l15, c1 = w * 32 + 16 + l15;
            float bb0 = b1l[c0], bb1 = b1l[c1];
            #pragma unroll
            for (int r = 0; r < 4; ++r) {
                hL[lq * 4 + r][c0]      = f2bf(fmaxf(acc00[r] + bb0, 0.f));
                hL[lq * 4 + r][c1]      = f2bf(fmaxf(acc01[r] + bb1, 0.f));
                hL[16 + lq * 4 + r][c0] = f2bf(fmaxf(acc10[r] + bb0, 0.f));
                hL[16 + lq * 4 + r][c1] = f2bf(fmaxf(acc11[r] + bb1, 0.f));
            }
        }
        __syncthreads();
        f32x4 o0 = {}, o1 = {};
        #pragma unroll
        for (int kk = 0; kk < 4; ++kk) {
            int kb = kk * 32 + lq * 8;
            bf16x8 h0 = *(const bf16x8*)&hL[l15][kb];
            bf16x8 h1 = *(const bf16x8*)&hL[16 + l15][kb];
            bf16x8 bw = *(const bf16x8*)&w2t[w * 16 + l15][kb];
            o0 = __builtin_amdgcn_mfma_f32_16x16x32_bf16(h0, bw, o0, 0, 0, 0);
            o1 = __builtin_amdgcn_mfma_f32_16x16x32_bf16(h1, bw, o1, 0, 0, 0);
        }
        #pragma unroll
        for (int r = 0; r < 4; ++r) {
            int row = row0 + lq * 4 + r;
            if (row < n_nodes)
                hv[(size_t)row * DIM + w * 16 + l15] = o0[r] * dinv[row];
            int row2 = row + 16;
            if (row2 < n_nodes)
                hv[(size_t)row2 * DIM + w * 16 + l15] = o1[r] * dinv[row2];
        }
        __syncthreads();
    }
}

// ---- fused layer-2 gather + final, batch-wide only --------------------------
__global__ __launch_bounds__(256) void item_final(const int* __restrict__ rowptr,
                                                  const int* __restrict__ srcs,
                                                  const float* __restrict__ dinv,
                                                  const float* __restrict__ hv,
                                                  const float* __restrict__ b2,
                                                  const float* __restrict__ user_emb,
                                                  const int* __restrict__ u,
                                                  const int* __restrict__ iid,
                                                  float* __restrict__ out,
                                                  int batch) {
    int lane = threadIdx.x & 63;
    int b = (blockIdx.x * 256 + threadIdx.x) >> 6;
    if (b >= batch) return;
    int ii = iid[b], uu = u[b];
    float uv = user_emb[(size_t)uu * DIM + lane];
    float s = uv * uv;
    #pragma unroll
    for (int off = 32; off; off >>= 1) s += __shfl_xor(s, off);
    float sc = fminf(1.0f, 1.0f / (sqrtf(s) + 1e-7f));
    float acc = hv[(size_t)ii * DIM + lane];
    int beg = rowptr[ii], end = rowptr[ii + 1];
    int p = beg;
    for (; p + 1 < end; p += 2) {
        int s0 = srcs[p], s1 = srcs[p + 1];
        acc += hv[(size_t)s0 * DIM + lane] + hv[(size_t)s1 * DIM + lane];
    }
    if (p < end) acc += hv[(size_t)srcs[p] * DIM + lane];
    float item = dinv[ii] * acc + b2[lane];
    float dot = uv * sc * item;
    #pragma unroll
    for (int off = 32; off; off >>= 1) dot += __shfl_xor(dot, off);
    if (lane == 0) out[b] = 1.0f / (1.0f + expf(-dot));
}

extern "C" void kernel_launch(void* const* d_in, const int* in_sizes, int n_in,
                              void* d_out, int out_size, void* d_ws, size_t ws_size,
                              hipStream_t stream) {
    const float* entity = (const float*)d_in[0];
    const float* user   = (const float*)d_in[1];
    const float* W1     = (const float*)d_in[2];
    const float* b1     = (const float*)d_in[3];
    const float* W2     = (const float*)d_in[4];
    const float* b2     = (const float*)d_in[5];
    const int*   u      = (const int*)d_in[6];
    const int*   iid    = (const int*)d_in[7];
    const int*   eidx   = (const int*)d_in[8];

    int N = in_sizes[0] / DIM;      // 100000
    int B = in_sizes[6];            // 8192
    int E = in_sizes[8] / 2;        // 1600000
    const int* src = eidx;
    const int* dst = eidx + E;
    int NB = (N + 1023) / 1024;     // 98 (<= 1024)
    int ntiles = (N + 31) / 32;     // 3125
    int rsize = (N + NRANGE - 1) / NRANGE;   // 12500

    // workspace layout, 16B-aligned segments
    char* p = (char*)d_ws;
    auto alloc = [&](size_t bytes) { char* r = p; p += (bytes + 15) & ~(size_t)15; return r; };
    int*   cnt    = (int*)alloc((size_t)N * 4);
    int*   rowptr = (int*)alloc((size_t)(N + 1) * 4);
    int*   bsum   = (int*)alloc((size_t)NB * 4);
    int*   boff   = (int*)alloc((size_t)(NB + 1) * 4);
    float* dinv   = (float*)alloc((size_t)N * 4);
    int*   srcs   = (int*)alloc((size_t)E * 4);
    unsigned short* xv = (unsigned short*)alloc((size_t)N * DIM * 2);
    unsigned short* ax = (unsigned short*)alloc((size_t)N * DIM * 2);
    float* hv     = (float*)alloc((size_t)N * DIM * 4);
    float* outF   = (float*)d_out;

    zero_cnt<<<NB, 1024, 0, stream>>>(cnt, N);
    hist_kernel<<<1024, 256, 0, stream>>>(dst, cnt, E);
    scan1<<<NB, 1024, 0, stream>>>(cnt, rowptr, bsum, dinv, N);
    scan2<<<1, 1024, 0, stream>>>(bsum, boff, NB);
    scan3<<<NB, 1024, 0, stream>>>(rowptr, boff, N, NB);
    node_init<<<(N * 64 + 255) / 256, 256, 0, stream>>>(entity, dinv, xv, N);
    place_kernel<<<2048, 256, 0, stream>>>(src, dst, rowptr, cnt, srcs, E, rsize);
    gather_ax<<<(N * 64 + 255) / 256, 256, 0, stream>>>(rowptr, srcs, dinv,
                                                        (const unsigned*)xv, (unsigned*)ax, N);
    mfma_mlp<<<512, 256, 0, stream>>>(ax, W1, b1, W2, dinv, hv, N, ntiles);
    item_final<<<(B * 64 + 255) / 256, 256, 0, stream>>>(rowptr, srcs, dinv, hv, b2, user, u, iid, outF, B);
}